// Round 17
// baseline (1030.823 us; speedup 1.0000x reference)
//
#include <hip/hip_runtime.h>
#include <hip/hip_bf16.h>
#include <stdint.h>

#define BATCH 64
#define SEQ   2048
#define HID   1024
#define EDIM  2048   // 2*HID

#define BM 64         // V0 rows per block
#define BN 512        // V0 cols per block (n-split = 2)
#define BK 32
#define KSTEPS (EDIM / BK)   // 64
#define BS (BATCH * SEQ)
#define NKT 32        // V1: K-tiles of 64

typedef __bf16 bf16x8 __attribute__((ext_vector_type(8)));
typedef float  f32x4a __attribute__((ext_vector_type(4)));

__device__ __forceinline__ unsigned short f2bf(float x) {
    __hip_bfloat16 h = __float2bfloat16(x);
    return __builtin_bit_cast(unsigned short, h);
}

__device__ __forceinline__ uint2 pack4(f32x4a f) {
    uint2 r;
    r.x = (unsigned)f2bf(f.x) | ((unsigned)f2bf(f.y) << 16);
    r.y = (unsigned)f2bf(f.z) | ((unsigned)f2bf(f.w) << 16);
    return r;
}

__device__ __forceinline__ uint4 pack8(f32x4a f0, f32x4a f1) {
    uint4 r;
    r.x = (unsigned)f2bf(f0.x) | ((unsigned)f2bf(f0.y) << 16);
    r.y = (unsigned)f2bf(f0.z) | ((unsigned)f2bf(f0.w) << 16);
    r.z = (unsigned)f2bf(f1.x) | ((unsigned)f2bf(f1.y) << 16);
    r.w = (unsigned)f2bf(f1.z) | ((unsigned)f2bf(f1.w) << 16);
    return r;
}

__device__ __forceinline__ f32x4a ntload4(const float* p) {
    return __builtin_nontemporal_load((const f32x4a*)p);
}

// V0 A-tile LDS addrs (verified R11/R13)
__device__ __forceinline__ int a_waddr(int row, int c) {
    return (row << 6) + ((c ^ (row & 6)) << 3);
}
__device__ __forceinline__ int a_raddr(int row, int g) {
    return (row << 6) + ((g ^ ((row >> 1) & 3)) << 4);
}

// ---------------- prep: W_h (EDIM x HID fp32) -> Wt bf16 granule-major:
// element (h,e) at Wt[(e>>3)*8192 + h*8 + (e&7)]
__global__ void wh_transpose_kernel(const float* __restrict__ Wh,
                                    unsigned short* __restrict__ Wt) {
    __shared__ float tile[32][33];
    int bx = blockIdx.x & 63;    // e-tile
    int by = blockIdx.x >> 6;    // h-tile
    int e0 = bx * 32, h0 = by * 32;
    int tx = threadIdx.x & 31, ty = threadIdx.x >> 5;   // 32 x 8
    #pragma unroll
    for (int i = 0; i < 4; ++i)
        tile[ty + 8 * i][tx] = Wh[(size_t)(e0 + ty + 8 * i) * HID + h0 + tx];
    __syncthreads();
    if (ty < 4) {
        uint4 wv;
        unsigned short* ws = (unsigned short*)&wv;
        #pragma unroll
        for (int j = 0; j < 8; ++j) ws[j] = f2bf(tile[ty * 8 + j][tx]);
        *(uint4*)&Wt[(size_t)((e0 >> 3) + ty) * 8192 + (size_t)(h0 + tx) * 8] = wv;
    }
}

// ---------------- prep: dec_proj = decoder_hidden @ W_d  (fp32, (B,HID))
__global__ void dec_proj_kernel(const float* __restrict__ dec,
                                const float* __restrict__ Wd,
                                float* __restrict__ dp) {
    int gid = blockIdx.x * 256 + threadIdx.x;
    int b = gid >> 10, h = gid & 1023;
    const float* dr = dec + b * HID;
    float acc = 0.f;
    #pragma unroll 4
    for (int k = 0; k < HID; ++k) acc = fmaf(dr[k], Wd[(size_t)k * HID + h], acc);
    dp[gid] = acc;
}

#define MFMA16(a, bfv, c) __builtin_amdgcn_mfma_f32_16x16x32_bf16(a, bfv, c, 0, 0, 0)

// ---------------- V0 (R13 verified): 64x512, B reg-dbuf, raw-barrier pipeline
#define KSTEP(kk, BCUR, BNXT, CURBUF, NXTBUF)                                   \
  {                                                                             \
    if ((kk) + 1 < KSTEPS) {                                                    \
      const unsigned short* bs = bptr + (size_t)((kk) + 1) * 32768;             \
      _Pragma("unroll")                                                         \
      for (int nj = 0; nj < 4; ++nj)                                            \
        BNXT[nj] = *(const bf16x8*)(bs + nj * 128);                             \
    }                                                                           \
    __builtin_amdgcn_s_setprio(1);                                              \
    _Pragma("unroll")                                                           \
    for (int mi = 0; mi < 4; ++mi) {                                            \
      bf16x8 afr = *(const bf16x8*)(CURBUF + a_raddr(mi * 16 + c15, g4));       \
      _Pragma("unroll")                                                         \
      for (int nj = 0; nj < 4; ++nj)                                            \
        acc[mi][nj] = MFMA16(afr, BCUR[nj], acc[mi][nj]);                       \
    }                                                                           \
    __builtin_amdgcn_s_setprio(0);                                              \
    if ((kk) + 1 < KSTEPS) *(uint2*)(NXTBUF + wb) = pack4(aL);                  \
    if ((kk) + 2 < KSTEPS) aL = ntload4(ap0 + ((kk) + 2) * BK);                 \
    asm volatile("s_waitcnt lgkmcnt(0)" ::: "memory");                          \
    __builtin_amdgcn_s_barrier();                                               \
    __builtin_amdgcn_sched_barrier(0);                                          \
  }

__global__ __launch_bounds__(512, 4) void scores_v0(
    const float* __restrict__ enc, const float* __restrict__ cov,
    const unsigned short* __restrict__ Wt, const float* __restrict__ dp,
    const float* __restrict__ Wc, const float* __restrict__ vv,
    float* __restrict__ spart_out)
{
    __shared__ char Al[2][4096];
    __shared__ float cov_s[BM];
    __shared__ float sred[BM][8];

    const int tid  = threadIdx.x;
    const int lane = tid & 63;
    const int wid  = tid >> 6;
    const int c15  = lane & 15;
    const int g4   = lane >> 4;

    const int bid  = blockIdx.x;
    const int half = bid & 1;
    const int m    = bid >> 1;                 // 0..1023 -> b 0..31
    const int b    = m >> 5;
    const int s0   = (m & 31) * BM;

    const float* Abase = enc + (size_t)(b * SEQ + s0) * EDIM;
    const int arow = tid >> 3;
    const int ac   = tid & 7;
    const float* ap0 = Abase + (size_t)arow * EDIM + ac * 4;
    const int wb = a_waddr(arow, ac);

    const unsigned short* bptr =
        Wt + (size_t)g4 * 8192 + (size_t)(half * BN + wid * 64 + c15) * 8;

    f32x4a acc[4][4];
    #pragma unroll
    for (int mi = 0; mi < 4; ++mi)
        #pragma unroll
        for (int nj = 0; nj < 4; ++nj)
            #pragma unroll
            for (int r = 0; r < 4; ++r) acc[mi][nj][r] = 0.f;

    if (tid < BM) cov_s[tid] = cov[b * SEQ + s0 + tid];

    bf16x8 bA[4], bB[4];
    f32x4a aL = ntload4(ap0);
    #pragma unroll
    for (int nj = 0; nj < 4; ++nj)
        bA[nj] = *(const bf16x8*)(bptr + nj * 128);
    *(uint2*)(Al[0] + wb) = pack4(aL);
    aL = ntload4(ap0 + BK);
    asm volatile("s_waitcnt lgkmcnt(0)" ::: "memory");
    __builtin_amdgcn_s_barrier();
    __builtin_amdgcn_sched_barrier(0);

    for (int kk2 = 0; kk2 < KSTEPS; kk2 += 2) {
        KSTEP(kk2,     bA, bB, Al[0], Al[1]);
        KSTEP(kk2 + 1, bB, bA, Al[1], Al[0]);
    }

    float spart[4][4];
    #pragma unroll
    for (int mi = 0; mi < 4; ++mi)
        #pragma unroll
        for (int r = 0; r < 4; ++r) spart[mi][r] = 0.f;

    #pragma unroll
    for (int nj = 0; nj < 4; ++nj) {
        const int h = half * BN + wid * 64 + nj * 16 + c15;
        const float dv  = dp[b * HID + h];
        const float wcv = Wc[h];
        const float vvv = vv[h];
        #pragma unroll
        for (int mi = 0; mi < 4; ++mi) {
            #pragma unroll
            for (int r = 0; r < 4; ++r) {
                const int row = mi * 16 + g4 * 4 + r;
                float pre = acc[mi][nj][r] + dv + cov_s[row] * wcv;
                float pc = fminf(pre, 20.0f);
                float e2 = __expf(2.0f * pc);
                spart[mi][r] = fmaf((e2 - 1.0f) / (e2 + 1.0f), vvv, spart[mi][r]);
            }
        }
    }
    #pragma unroll
    for (int mi = 0; mi < 4; ++mi) {
        #pragma unroll
        for (int r = 0; r < 4; ++r) {
            float x = spart[mi][r];
            x += __shfl_xor(x, 1);
            x += __shfl_xor(x, 2);
            x += __shfl_xor(x, 4);
            x += __shfl_xor(x, 8);
            if (c15 == 0) sred[mi * 16 + g4 * 4 + r][wid] = x;
        }
    }
    __syncthreads();
    if (tid < BM) {
        float s = 0.f;
        #pragma unroll
        for (int w = 0; w < 8; ++w) s += sred[tid][w];
        spart_out[(size_t)half * BS + b * SEQ + s0 + tid] = s;
    }
}

// ---------------- V1 (test): 256x256 tile, 4-phase quadrant split, 8 waves,
// wave-tile 128x64, B L2->regs once per K-tile (reused 4 phases), A reg-relay
// -> LDS dbuf (R13 pattern), raw barriers, no vmcnt drain. 1 block/CU.
#define V1PHASE(p, ASa, ASb)                                                    \
  {                                                                             \
    bf16x8 afr[2][2];                                                           \
    _Pragma("unroll")                                                           \
    for (int i = 0; i < 2; ++i) {                                               \
      const int row = wm * 128 + (2 * (p) + i) * 16 + c15;                      \
      _Pragma("unroll")                                                         \
      for (int ks = 0; ks < 2; ++ks) {                                          \
        const int g = ks * 4 + g4;                                              \
        afr[i][ks] = *(const bf16x8*)(Acur + row * 128 + ((g ^ (row & 7)) << 4)); \
      }                                                                         \
    }                                                                           \
    asm volatile("s_waitcnt lgkmcnt(0)" ::: "memory");                          \
    __builtin_amdgcn_sched_barrier(0);                                          \
    __builtin_amdgcn_s_setprio(1);                                              \
    _Pragma("unroll")                                                           \
    for (int ks = 0; ks < 2; ++ks)                                              \
      _Pragma("unroll")                                                         \
      for (int i = 0; i < 2; ++i)                                               \
        _Pragma("unroll")                                                       \
        for (int nj = 0; nj < 4; ++nj)                                          \
          acc[2 * (p) + i][nj] =                                                \
              MFMA16(afr[i][ks], bfr[ks][nj], acc[2 * (p) + i][nj]);            \
    __builtin_amdgcn_s_setprio(0);                                              \
    if (t < NKT - 1) {                                                          \
      const int rw = (p) * 64 + ar;                                             \
      *(uint4*)(Anxt + rw * 128 + ((ag ^ (rw & 7)) << 4)) = pack8(ASa, ASb);    \
      int ktl = ((p) < 2) ? (t + 1) : (t + 2);                                  \
      if (ktl >= NKT) ktl = 0;                                                  \
      const int rq = ((((p) < 2) ? ((p) + 2) : ((p) - 2))) * 64 + ar;           \
      const float* ap = Abase + (size_t)rq * EDIM + ktl * 64 + ag * 8;          \
      ASa = *(const f32x4a*)ap;                                                 \
      ASb = *(const f32x4a*)(ap + 4);                                           \
    }                                                                           \
    if ((p) == 3) asm volatile("s_waitcnt lgkmcnt(0)" ::: "memory");            \
    __builtin_amdgcn_s_barrier();                                               \
    __builtin_amdgcn_sched_barrier(0);                                          \
  }

__global__ __launch_bounds__(512, 2) void scores_v1(
    const float* __restrict__ enc, const float* __restrict__ cov,
    const unsigned short* __restrict__ Wt, const float* __restrict__ dp,
    const float* __restrict__ Wc, const float* __restrict__ vv,
    float* __restrict__ spartB)
{
    extern __shared__ char smem[];     // A dbuf 2 x 32768 B; sred overlays after

    const int tid  = threadIdx.x;
    const int lane = tid & 63;
    const int wid  = tid >> 6;       // 0..7
    const int wm   = wid >> 2;       // 0..1 : 128-row half
    const int wn   = wid & 3;        // 0..3 : 64-col slice
    const int c15  = lane & 15;
    const int g4   = lane >> 4;

    const int nt = blockIdx.x & 3;
    const int mt = 256 + (blockIdx.x >> 2);   // b 32..63
    const int b  = mt >> 3;
    const int s0 = (mt & 7) * 256;

    const float* Abase = enc + (size_t)(b * SEQ + s0) * EDIM;
    const int ar = tid >> 3;      // 0..63 : row within quarter
    const int ag = tid & 7;       // granule

    const unsigned short* Bbase =
        Wt + (size_t)g4 * 8192 + (size_t)(nt * 256 + wn * 64 + c15) * 8;

    f32x4a acc[8][4];
    #pragma unroll
    for (int mi = 0; mi < 8; ++mi)
        #pragma unroll
        for (int nj = 0; nj < 4; ++nj)
            #pragma unroll
            for (int r = 0; r < 4; ++r) acc[mi][nj][r] = 0.f;

    // prologue: A[0] -> buf0 (4 quarters); aR0 <- A[1]q0, aR1 <- A[1]q1
    #pragma unroll
    for (int q = 0; q < 4; ++q) {
        const int r = q * 64 + ar;
        const float* ap = Abase + (size_t)r * EDIM + ag * 8;
        f32x4a t0 = *(const f32x4a*)ap;
        f32x4a t1 = *(const f32x4a*)(ap + 4);
        *(uint4*)(smem + r * 128 + ((ag ^ (r & 7)) << 4)) = pack8(t0, t1);
    }
    f32x4a aR0a, aR0b, aR1a, aR1b;
    {
        const float* p0 = Abase + (size_t)ar * EDIM + 64 + ag * 8;
        aR0a = *(const f32x4a*)p0; aR0b = *(const f32x4a*)(p0 + 4);
        const float* p1 = Abase + (size_t)(64 + ar) * EDIM + 64 + ag * 8;
        aR1a = *(const f32x4a*)p1; aR1b = *(const f32x4a*)(p1 + 4);
    }
    asm volatile("s_waitcnt lgkmcnt(0)" ::: "memory");
    __builtin_amdgcn_s_barrier();
    __builtin_amdgcn_sched_barrier(0);

    for (int t = 0; t < NKT; ++t) {
        char* Acur = smem + (t & 1) * 32768;
        char* Anxt = smem + ((t & 1) ^ 1) * 32768;
        // B fragments for this K-tile straight from L2, reused by all 4 phases
        bf16x8 bfr[2][4];
        const unsigned short* bs = Bbase + (size_t)t * 8 * 8192;
        #pragma unroll
        for (int ks = 0; ks < 2; ++ks)
            #pragma unroll
            for (int nj = 0; nj < 4; ++nj)
                bfr[ks][nj] = *(const bf16x8*)(bs + (size_t)ks * 4 * 8192 + nj * 128);

        V1PHASE(0, aR0a, aR0b)
        V1PHASE(1, aR1a, aR1b)
        V1PHASE(2, aR0a, aR0b)
        V1PHASE(3, aR1a, aR1b)
    }

    // epilogue: tanh(acc + dp + cov*Wc) . v, partial per n-tile
    __syncthreads();
    float* sred = (float*)smem;        // [256][4] overlay (A buffers dead)
    float dpv[4], wcv[4], vvv[4];
    #pragma unroll
    for (int nj = 0; nj < 4; ++nj) {
        const int h = nt * 256 + wn * 64 + nj * 16 + c15;
        dpv[nj] = dp[b * HID + h];
        wcv[nj] = Wc[h];
        vvv[nj] = vv[h];
    }
    #pragma unroll
    for (int mi = 0; mi < 8; ++mi) {
        #pragma unroll
        for (int r = 0; r < 4; ++r) {
            const int row = wm * 128 + mi * 16 + g4 * 4 + r;
            const float cv = cov[b * SEQ + s0 + row];
            float x = 0.f;
            #pragma unroll
            for (int nj = 0; nj < 4; ++nj) {
                float pre = acc[mi][nj][r] + dpv[nj] + cv * wcv[nj];
                float pc = fminf(pre, 20.0f);
                float e2 = __expf(2.0f * pc);
                x = fmaf((e2 - 1.0f) / (e2 + 1.0f), vvv[nj], x);
            }
            x += __shfl_xor(x, 1);
            x += __shfl_xor(x, 2);
            x += __shfl_xor(x, 4);
            x += __shfl_xor(x, 8);
            if (c15 == 0) sred[row * 4 + wn] = x;
        }
    }
    __syncthreads();
    if (tid < 256) {
        float s = sred[tid * 4] + sred[tid * 4 + 1] +
                  sred[tid * 4 + 2] + sred[tid * 4 + 3];
        spartB[(size_t)nt * BS + b * SEQ + s0 + tid] = s;
    }
}

// ---------------- softmax + coverage_new (V0: 2 partials; V1: 4 partials)
__global__ void softmax_kernel(const float* __restrict__ spartA,
                               const float* __restrict__ spartB,
                               const int* __restrict__ mask,
                               const float* __restrict__ cov,
                               float* __restrict__ out)
{
    __shared__ float red[8];
    int b = blockIdx.x, tid = threadIdx.x;   // 256 threads
    float vals[8];
    float mx = -1e30f;
    #pragma unroll
    for (int i = 0; i < 8; ++i) {
        int s = tid + i * 256;
        float sc;
        if (b < 32) {
            sc = spartA[b * SEQ + s] + spartA[BS + b * SEQ + s];
        } else {
            sc = spartB[b * SEQ + s] + spartB[(size_t)BS + b * SEQ + s] +
                 spartB[2 * (size_t)BS + b * SEQ + s] +
                 spartB[3 * (size_t)BS + b * SEQ + s];
        }
        sc = (mask[b * SEQ + s] == 0) ? -10000.0f : sc;
        vals[i] = sc;
        mx = fmaxf(mx, sc);
    }
    for (int m = 1; m < 64; m <<= 1) mx = fmaxf(mx, __shfl_xor(mx, m));
    if ((tid & 63) == 0) red[tid >> 6] = mx;
    __syncthreads();
    mx = fmaxf(fmaxf(red[0], red[1]), fmaxf(red[2], red[3]));
    float sum = 0.f;
    #pragma unroll
    for (int i = 0; i < 8; ++i) { vals[i] = __expf(vals[i] - mx); sum += vals[i]; }
    for (int m = 1; m < 64; m <<= 1) sum += __shfl_xor(sum, m);
    if ((tid & 63) == 0) red[4 + (tid >> 6)] = sum;
    __syncthreads();
    sum = red[4] + red[5] + red[6] + red[7];
    float inv = 1.0f / sum;
    float* attn = out + BATCH * EDIM;
    float* covn = attn + BATCH * SEQ;
    #pragma unroll
    for (int i = 0; i < 8; ++i) {
        int s = tid + i * 256;
        float w = vals[i] * inv;
        attn[b * SEQ + s] = w;
        covn[b * SEQ + s] = cov[b * SEQ + s] + w;
    }
}

// ---------------- context partials: (b, e-slice, s-chunk) -> cpart
__global__ void context_partial_kernel(const float* __restrict__ enc,
                                       const float* __restrict__ attn,
                                       float* __restrict__ cpart)
{
    __shared__ float w_s[512];
    int bid = blockIdx.x;
    int sc = bid & 3;
    int e0 = ((bid >> 2) & 7) * 256;
    int b  = bid >> 5;
    int tid = threadIdx.x;
    w_s[tid] = attn[b * SEQ + sc * 512 + tid];
    w_s[tid + 256] = attn[b * SEQ + sc * 512 + 256 + tid];
    __syncthreads();
    const float* ep = enc + ((size_t)b * SEQ + sc * 512) * EDIM + e0 + tid;
    float acc = 0.f;
    #pragma unroll 8
    for (int s = 0; s < 512; ++s)
        acc = fmaf(w_s[s], __builtin_nontemporal_load(ep + (size_t)s * EDIM), acc);
    cpart[((size_t)sc * BATCH + b) * EDIM + e0 + tid] = acc;
}

__global__ void ctx_reduce_kernel(const float* __restrict__ cpart,
                                  float* __restrict__ ctx)
{
    int idx = blockIdx.x * 256 + threadIdx.x;
    ctx[idx] = cpart[idx] + cpart[BATCH * EDIM + idx] +
               cpart[2 * BATCH * EDIM + idx] + cpart[3 * BATCH * EDIM + idx];
}

extern "C" void kernel_launch(void* const* d_in, const int* in_sizes, int n_in,
                              void* d_out, int out_size, void* d_ws, size_t ws_size,
                              hipStream_t stream) {
    const float* dec  = (const float*)d_in[0];
    const float* enc  = (const float*)d_in[1];
    const float* cov  = (const float*)d_in[2];
    const int*   mask = (const int*)d_in[3];
    const float* Wh   = (const float*)d_in[4];
    const float* Wd   = (const float*)d_in[5];
    const float* Wc   = (const float*)d_in[6];
    const float* v    = (const float*)d_in[7];
    float* out = (float*)d_out;

    unsigned short* Wt = (unsigned short*)d_ws;                        // 4 MiB bf16
    float* dp     = (float*)((char*)d_ws + (size_t)HID * EDIM * 2);    // 256 KiB
    float* spartA = dp + BATCH * HID;                                  // 2 x BS
    float* spartB = spartA + 2 * BS;                                   // 4 x BS
    float* cpart  = spartB + 4 * BS;                                   // 2 MiB

    (void)hipFuncSetAttribute((const void*)scores_v1,
                              hipFuncAttributeMaxDynamicSharedMemorySize, 65536);

    wh_transpose_kernel<<<dim3(64 * 32), dim3(256), 0, stream>>>(Wh, Wt);
    dec_proj_kernel<<<dim3(BATCH * HID / 256), dim3(256), 0, stream>>>(dec, Wd, dp);
    // A/B: V0 (R13) on b<32; V1 (256^2 4-phase) on b>=32
    scores_v0<<<dim3(2048), dim3(512), 0, stream>>>(enc, cov, Wt, dp, Wc, v, spartA);
    scores_v1<<<dim3(1024), dim3(512), 65536, stream>>>(enc, cov, Wt, dp, Wc, v, spartB);
    softmax_kernel<<<dim3(BATCH), dim3(256), 0, stream>>>(spartA, spartB, mask, cov, out);
    context_partial_kernel<<<dim3(BATCH * 8 * 4), dim3(256), 0, stream>>>(
        enc, out + BATCH * EDIM, cpart);
    ctx_reduce_kernel<<<dim3(BATCH * EDIM / 256), dim3(256), 0, stream>>>(cpart, out);
}

// Round 18
// 984.983 us; speedup vs baseline: 1.0465x; 1.0465x over previous
//
#include <hip/hip_runtime.h>
#include <hip/hip_bf16.h>
#include <stdint.h>

#define BATCH 64
#define SEQ   2048
#define HID   1024
#define EDIM  2048   // 2*HID

#define BM 64         // rows per block
#define BN 512        // cols per block (n-split = 2)
#define BK 32
#define KSTEPS (EDIM / BK)   // 64
#define BS (BATCH * SEQ)

typedef __bf16 bf16x8 __attribute__((ext_vector_type(8)));
typedef float  f32x4a __attribute__((ext_vector_type(4)));

__device__ __forceinline__ unsigned short f2bf(float x) {
    __hip_bfloat16 h = __float2bfloat16(x);
    return __builtin_bit_cast(unsigned short, h);
}

__device__ __forceinline__ uint2 pack4(f32x4a f) {
    uint2 r;
    r.x = (unsigned)f2bf(f.x) | ((unsigned)f2bf(f.y) << 16);
    r.y = (unsigned)f2bf(f.z) | ((unsigned)f2bf(f.w) << 16);
    return r;
}

__device__ __forceinline__ f32x4a ntload4(const float* p) {
    return __builtin_nontemporal_load((const f32x4a*)p);
}

// A-tile LDS addrs (verified R11/R13): write 8B chunks, read 16B granules
__device__ __forceinline__ int a_waddr(int row, int c) {
    return (row << 6) + ((c ^ (row & 6)) << 3);
}
__device__ __forceinline__ int a_raddr(int row, int g) {
    return (row << 6) + ((g ^ ((row >> 1) & 3)) << 4);
}

// ---------------- prep: W_h (EDIM x HID fp32) -> Wt bf16 granule-major:
// element (h,e) at Wt[(e>>3)*8192 + h*8 + (e&7)]  (fragment = contiguous 16B)
__global__ void wh_transpose_kernel(const float* __restrict__ Wh,
                                    unsigned short* __restrict__ Wt) {
    __shared__ float tile[32][33];
    int bx = blockIdx.x & 63;    // e-tile
    int by = blockIdx.x >> 6;    // h-tile
    int e0 = bx * 32, h0 = by * 32;
    int tx = threadIdx.x & 31, ty = threadIdx.x >> 5;   // 32 x 8
    #pragma unroll
    for (int i = 0; i < 4; ++i)
        tile[ty + 8 * i][tx] = Wh[(size_t)(e0 + ty + 8 * i) * HID + h0 + tx];
    __syncthreads();
    if (ty < 4) {
        uint4 wv;
        unsigned short* ws = (unsigned short*)&wv;
        #pragma unroll
        for (int j = 0; j < 8; ++j) ws[j] = f2bf(tile[ty * 8 + j][tx]);
        *(uint4*)&Wt[(size_t)((e0 >> 3) + ty) * 8192 + (size_t)(h0 + tx) * 8] = wv;
    }
}

// ---------------- prep: dec_proj = decoder_hidden @ W_d  (fp32, (B,HID))
__global__ void dec_proj_kernel(const float* __restrict__ dec,
                                const float* __restrict__ Wd,
                                float* __restrict__ dp) {
    int gid = blockIdx.x * 256 + threadIdx.x;
    int b = gid >> 10, h = gid & 1023;
    const float* dr = dec + b * HID;
    float acc = 0.f;
    #pragma unroll 4
    for (int k = 0; k < HID; ++k) acc = fmaf(dr[k], Wd[(size_t)k * HID + h], acc);
    dp[gid] = acc;
}

#define MFMA16(a, bfv, c) __builtin_amdgcn_mfma_f32_16x16x32_bf16(a, bfv, c, 0, 0, 0)

// One pipelined k-step: consume BCUR, prefetch BNXT (loads cross the raw barrier)
#define KSTEP(kk, BCUR, BNXT, CURBUF, NXTBUF)                                   \
  {                                                                             \
    if ((kk) + 1 < KSTEPS) {                                                    \
      const unsigned short* bs = bptr + (size_t)((kk) + 1) * 32768;             \
      _Pragma("unroll")                                                         \
      for (int nj = 0; nj < 4; ++nj)                                            \
        BNXT[nj] = *(const bf16x8*)(bs + nj * 128);                             \
    }                                                                           \
    __builtin_amdgcn_s_setprio(1);                                              \
    _Pragma("unroll")                                                           \
    for (int mi = 0; mi < 4; ++mi) {                                            \
      bf16x8 afr = *(const bf16x8*)(CURBUF + a_raddr(mi * 16 + c15, g4));       \
      _Pragma("unroll")                                                         \
      for (int nj = 0; nj < 4; ++nj)                                            \
        acc[mi][nj] = MFMA16(afr, BCUR[nj], acc[mi][nj]);                       \
    }                                                                           \
    __builtin_amdgcn_s_setprio(0);                                              \
    if ((kk) + 1 < KSTEPS) *(uint2*)(NXTBUF + wb) = pack4(aL);                  \
    if ((kk) + 2 < KSTEPS) aL = ntload4(ap0 + ((kk) + 2) * BK);                 \
    asm volatile("s_waitcnt lgkmcnt(0)" ::: "memory");                          \
    __builtin_amdgcn_s_barrier();                                               \
    __builtin_amdgcn_sched_barrier(0);                                          \
  }

// ---------------- main fused scores kernel: 64 rows x 512 cols, 8 waves,
// raw-barrier pipeline: B(k+1) regs + A(k+2) reg in flight ACROSS the barrier
// (no vmcnt(0) drain). 2 blocks/CU. [R13/R15 verified: 757-762us scores]
__global__ __launch_bounds__(512, 4) void scores_kernel(
    const float* __restrict__ enc, const float* __restrict__ cov,
    const unsigned short* __restrict__ Wt, const float* __restrict__ dp,
    const float* __restrict__ Wc, const float* __restrict__ vv,
    float* __restrict__ spart_out)
{
    __shared__ char Al[2][4096];       // A dbuf: 64 rows x 64B, swizzled
    __shared__ float cov_s[BM];
    __shared__ float sred[BM][8];

    const int tid  = threadIdx.x;
    const int lane = tid & 63;
    const int wid  = tid >> 6;       // 0..7 : 64-col slice
    const int c15  = lane & 15;
    const int g4   = lane >> 4;      // 0..3 : k-granule

    // bid pairs: (m, half=0/1) adjacent -> enc panel L3-hot on 2nd read
    const int bid  = blockIdx.x;
    const int half = bid & 1;
    const int m    = bid >> 1;                 // 0..2047
    const int b    = m >> 5;
    const int s0   = (m & 31) * BM;

    const float* Abase = enc + (size_t)(b * SEQ + s0) * EDIM;
    // A staging: ALL 512 threads, one f32x4 (16B fp32 -> 8B bf16) per k-step
    const int arow = tid >> 3;                 // 0..63
    const int ac   = tid & 7;                  // chunk of 4 floats
    const float* ap0 = Abase + (size_t)arow * EDIM + ac * 4;
    const int wb = a_waddr(arow, ac);

    // per-lane B base: granule g4, col h = half*512 + wid*64 + c15 (+16*nj)
    const unsigned short* bptr =
        Wt + (size_t)g4 * 8192 + (size_t)(half * BN + wid * 64 + c15) * 8;

    f32x4a acc[4][4];
    #pragma unroll
    for (int mi = 0; mi < 4; ++mi)
        #pragma unroll
        for (int nj = 0; nj < 4; ++nj)
            #pragma unroll
            for (int r = 0; r < 4; ++r) acc[mi][nj][r] = 0.f;

    if (tid < BM) cov_s[tid] = cov[b * SEQ + s0 + tid];

    // prologue: A(0)->LDS buf0, B(0)->bA, A(1)->reg
    bf16x8 bA[4], bB[4];
    f32x4a aL = ntload4(ap0);
    #pragma unroll
    for (int nj = 0; nj < 4; ++nj)
        bA[nj] = *(const bf16x8*)(bptr + nj * 128);
    *(uint2*)(Al[0] + wb) = pack4(aL);
    aL = ntload4(ap0 + BK);
    asm volatile("s_waitcnt lgkmcnt(0)" ::: "memory");
    __builtin_amdgcn_s_barrier();
    __builtin_amdgcn_sched_barrier(0);

    for (int kk2 = 0; kk2 < KSTEPS; kk2 += 2) {
        KSTEP(kk2,     bA, bB, Al[0], Al[1]);
        KSTEP(kk2 + 1, bB, bA, Al[1], Al[0]);
    }

    // epilogue: + dec_proj + cov*W_c -> tanh -> * v, reduce this block's 512 cols
    float spart[4][4];
    #pragma unroll
    for (int mi = 0; mi < 4; ++mi)
        #pragma unroll
        for (int r = 0; r < 4; ++r) spart[mi][r] = 0.f;

    #pragma unroll
    for (int nj = 0; nj < 4; ++nj) {
        const int h = half * BN + wid * 64 + nj * 16 + c15;
        const float dv  = dp[b * HID + h];
        const float wcv = Wc[h];
        const float vvv = vv[h];
        #pragma unroll
        for (int mi = 0; mi < 4; ++mi) {
            #pragma unroll
            for (int r = 0; r < 4; ++r) {
                const int row = mi * 16 + g4 * 4 + r;
                float pre = acc[mi][nj][r] + dv + cov_s[row] * wcv;
                float pc = fminf(pre, 20.0f);       // tanh(20)==1 in fp32
                float e2 = __expf(2.0f * pc);
                spart[mi][r] = fmaf((e2 - 1.0f) / (e2 + 1.0f), vvv, spart[mi][r]);
            }
        }
    }
    #pragma unroll
    for (int mi = 0; mi < 4; ++mi) {
        #pragma unroll
        for (int r = 0; r < 4; ++r) {
            float x = spart[mi][r];
            x += __shfl_xor(x, 1);
            x += __shfl_xor(x, 2);
            x += __shfl_xor(x, 4);
            x += __shfl_xor(x, 8);
            if (c15 == 0) sred[mi * 16 + g4 * 4 + r][wid] = x;
        }
    }
    __syncthreads();
    if (tid < BM) {
        float s = 0.f;
        #pragma unroll
        for (int w = 0; w < 8; ++w) s += sred[tid][w];
        spart_out[(size_t)half * BS + b * SEQ + s0 + tid] = s;
    }
}

// ---------------- softmax + coverage_new (sums the two N-half partial scores)
__global__ void softmax_kernel(const float* __restrict__ spart,
                               const int* __restrict__ mask,
                               const float* __restrict__ cov,
                               float* __restrict__ out)
{
    __shared__ float red[8];
    int b = blockIdx.x, tid = threadIdx.x;   // 256 threads
    float vals[8];
    float mx = -1e30f;
    #pragma unroll
    for (int i = 0; i < 8; ++i) {
        int s = tid + i * 256;
        float sc = spart[b * SEQ + s] + spart[BS + b * SEQ + s];
        sc = (mask[b * SEQ + s] == 0) ? -10000.0f : sc;
        vals[i] = sc;
        mx = fmaxf(mx, sc);
    }
    for (int m = 1; m < 64; m <<= 1) mx = fmaxf(mx, __shfl_xor(mx, m));
    if ((tid & 63) == 0) red[tid >> 6] = mx;
    __syncthreads();
    mx = fmaxf(fmaxf(red[0], red[1]), fmaxf(red[2], red[3]));
    float sum = 0.f;
    #pragma unroll
    for (int i = 0; i < 8; ++i) { vals[i] = __expf(vals[i] - mx); sum += vals[i]; }
    for (int m = 1; m < 64; m <<= 1) sum += __shfl_xor(sum, m);
    if ((tid & 63) == 0) red[4 + (tid >> 6)] = sum;
    __syncthreads();
    sum = red[4] + red[5] + red[6] + red[7];
    float inv = 1.0f / sum;
    float* attn = out + BATCH * EDIM;
    float* covn = attn + BATCH * SEQ;
    #pragma unroll
    for (int i = 0; i < 8; ++i) {
        int s = tid + i * 256;
        float w = vals[i] * inv;
        attn[b * SEQ + s] = w;
        covn[b * SEQ + s] = cov[b * SEQ + s] + w;
    }
}

// ---------------- context partials: (b, e-slice, s-chunk) -> cpart
__global__ void context_partial_kernel(const float* __restrict__ enc,
                                       const float* __restrict__ attn,
                                       float* __restrict__ cpart)
{
    __shared__ float w_s[512];
    int bid = blockIdx.x;
    int sc = bid & 3;            // S-chunk of 512
    int e0 = ((bid >> 2) & 7) * 256;
    int b  = bid >> 5;
    int tid = threadIdx.x;
    w_s[tid] = attn[b * SEQ + sc * 512 + tid];
    w_s[tid + 256] = attn[b * SEQ + sc * 512 + 256 + tid];
    __syncthreads();
    const float* ep = enc + ((size_t)b * SEQ + sc * 512) * EDIM + e0 + tid;
    float acc = 0.f;
    #pragma unroll 8
    for (int s = 0; s < 512; ++s)
        acc = fmaf(w_s[s], __builtin_nontemporal_load(ep + (size_t)s * EDIM), acc);
    cpart[((size_t)sc * BATCH + b) * EDIM + e0 + tid] = acc;
}

__global__ void ctx_reduce_kernel(const float* __restrict__ cpart,
                                  float* __restrict__ ctx)
{
    int idx = blockIdx.x * 256 + threadIdx.x;     // 0 .. B*EDIM
    ctx[idx] = cpart[idx] + cpart[BATCH * EDIM + idx] +
               cpart[2 * BATCH * EDIM + idx] + cpart[3 * BATCH * EDIM + idx];
}

extern "C" void kernel_launch(void* const* d_in, const int* in_sizes, int n_in,
                              void* d_out, int out_size, void* d_ws, size_t ws_size,
                              hipStream_t stream) {
    const float* dec  = (const float*)d_in[0];
    const float* enc  = (const float*)d_in[1];
    const float* cov  = (const float*)d_in[2];
    const int*   mask = (const int*)d_in[3];
    const float* Wh   = (const float*)d_in[4];
    const float* Wd   = (const float*)d_in[5];
    const float* Wc   = (const float*)d_in[6];
    const float* v    = (const float*)d_in[7];
    float* out = (float*)d_out;

    unsigned short* Wt = (unsigned short*)d_ws;                        // 4 MiB bf16
    float* dp    = (float*)((char*)d_ws + (size_t)HID * EDIM * 2);     // 256 KiB
    float* spart = dp + BATCH * HID;                                   // 1 MiB (2 halves)
    float* cpart = spart + 2 * BS;                                     // 2 MiB

    wh_transpose_kernel<<<dim3(64 * 32), dim3(256), 0, stream>>>(Wh, Wt);
    dec_proj_kernel<<<dim3(BATCH * HID / 256), dim3(256), 0, stream>>>(dec, Wd, dp);
    scores_kernel<<<dim3((BS / BM) * 2), dim3(512), 0, stream>>>(
        enc, cov, Wt, dp, Wc, v, spart);
    softmax_kernel<<<dim3(BATCH), dim3(256), 0, stream>>>(spart, mask, cov, out);
    context_partial_kernel<<<dim3(BATCH * 8 * 4), dim3(256), 0, stream>>>(
        enc, out + BATCH * EDIM, cpart);
    ctx_reduce_kernel<<<dim3(BATCH * EDIM / 256), dim3(256), 0, stream>>>(cpart, out);
}